// Round 1
// baseline (190.593 us; speedup 1.0000x reference)
//
#include <hip/hip_runtime.h>
#include <math.h>

#define NIMG 16
#define HH 512
#define WW 512
#define HW (HH*WW)   // 262144

// Sobel weights, replicating numpy f32 arithmetic exactly:
// S[i][j] = f32( f32(x/den) / 6 ), x=i-2, y=j-2, den = x*x+y*y except y==0 col -> 1
// Compile-time folding of float expressions is IEEE correctly-rounded per op.
__device__ __constant__ float WS5[25] = {
  -2.0f/8.0f/6.0f, -2.0f/5.0f/6.0f, -2.0f/1.0f/6.0f, -2.0f/5.0f/6.0f, -2.0f/8.0f/6.0f,
  -1.0f/5.0f/6.0f, -1.0f/2.0f/6.0f, -1.0f/1.0f/6.0f, -1.0f/2.0f/6.0f, -1.0f/5.0f/6.0f,
   0.0f,            0.0f,            0.0f,            0.0f,            0.0f,
   1.0f/5.0f/6.0f,  1.0f/2.0f/6.0f,  1.0f/1.0f/6.0f,  1.0f/2.0f/6.0f,  1.0f/5.0f/6.0f,
   2.0f/8.0f/6.0f,  2.0f/5.0f/6.0f,  2.0f/1.0f/6.0f,  2.0f/5.0f/6.0f,  2.0f/8.0f/6.0f
};

__device__ __forceinline__ int refl(int i) {
  // reflect (no edge repeat), |offset| <= 2 so single reflection suffices
  if (i < 0) return -i;
  if (i >= HH) return 2*HH - 2 - i;
  return i;
}

// K1: sumsq over 3 channels + global max of sumsq (bits trick, all values >= 0)
__global__ __launch_bounds__(256) void k1_sumsq(const float* __restrict__ img,
                                                float* __restrict__ ss,
                                                unsigned int* __restrict__ mx) {
  int gid = blockIdx.x * 256 + threadIdx.x;   // 0 .. 1048575 (float4 granules)
  int n  = gid >> 16;                         // 65536 float4 per image plane
  int p4 = gid & 65535;
  const float* base = img + (size_t)n * 3 * HW;
  float4 r = ((const float4*)(base        ))[p4];
  float4 g = ((const float4*)(base +   HW ))[p4];
  float4 b = ((const float4*)(base + 2*HW ))[p4];
  float4 s;
  s.x = __fadd_rn(__fadd_rn(__fmul_rn(r.x,r.x), __fmul_rn(g.x,g.x)), __fmul_rn(b.x,b.x));
  s.y = __fadd_rn(__fadd_rn(__fmul_rn(r.y,r.y), __fmul_rn(g.y,g.y)), __fmul_rn(b.y,b.y));
  s.z = __fadd_rn(__fadd_rn(__fmul_rn(r.z,r.z), __fmul_rn(g.z,g.z)), __fmul_rn(b.z,b.z));
  s.w = __fadd_rn(__fadd_rn(__fmul_rn(r.w,r.w), __fmul_rn(g.w,g.w)), __fmul_rn(b.w,b.w));
  ((float4*)ss)[gid] = s;

  float m = fmaxf(fmaxf(s.x, s.y), fmaxf(s.z, s.w));
  #pragma unroll
  for (int off = 32; off > 0; off >>= 1)
    m = fmaxf(m, __shfl_down(m, off));
  __shared__ float sm[4];
  int lane = threadIdx.x & 63, wv = threadIdx.x >> 6;
  if (lane == 0) sm[wv] = m;
  __syncthreads();
  if (threadIdx.x == 0) {
    m = fmaxf(fmaxf(sm[0], sm[1]), fmaxf(sm[2], sm[3]));
    atomicMax(mx, __float_as_uint(m));
  }
}

// K2: mag = sqrt(ss) / sqrt(max_ss), in place (element-wise)
__global__ __launch_bounds__(256) void k2_norm(float* __restrict__ ssmag,
                                               const unsigned int* __restrict__ mx) {
  int gid = blockIdx.x * 256 + threadIdx.x;
  float mm = sqrtf(__uint_as_float(*mx));
  float4 s = ((const float4*)ssmag)[gid];
  float4 o;
  o.x = __fdiv_rn(sqrtf(s.x), mm);
  o.y = __fdiv_rn(sqrtf(s.y), mm);
  o.z = __fdiv_rn(sqrtf(s.z), mm);
  o.w = __fdiv_rn(sqrtf(s.w), mm);
  ((float4*)ssmag)[gid] = o;
}

// K3: 5x5 Sobel (reflect pad, f64 accumulate), grad_mag, phase -> pair index
__global__ __launch_bounds__(256) void k3_sobel(const float* __restrict__ mag,
                                                float* __restrict__ sobel_out,
                                                float* __restrict__ gm,
                                                unsigned char* __restrict__ pairb) {
  int x = blockIdx.x * 64 + threadIdx.x;
  int y = blockIdx.y * 4  + threadIdx.y;
  int n = blockIdx.z;
  const float* mp = mag + (size_t)n * HW;
  double asy = 0.0, asx = 0.0;
  #pragma unroll
  for (int a = 0; a < 5; ++a) {
    int ry = refl(y + a - 2);
    const float* row = mp + ry * WW;
    #pragma unroll
    for (int b = 0; b < 5; ++b) {
      int rx = refl(x + b - 2);
      double v = (double)row[rx];
      asy += v * (double)WS5[a*5 + b];   // W_SY = S
      asx += v * (double)WS5[b*5 + a];   // W_SX = S^T
    }
  }
  float fsy = (float)asy, fsx = (float)asx;
  int p = y * WW + x;
  sobel_out[(size_t)n * 2 * HW + p]      = fsy;  // channel 0: sobel_y
  sobel_out[(size_t)n * 2 * HW + HW + p] = fsx;  // channel 1: sobel_x
  float g = sqrtf(__fadd_rn(__fmul_rn(fsx, fsx), __fmul_rn(fsy, fsy)));
  gm[(size_t)n * HW + p] = g;
  float ph = atan2f(fsx, __fadd_rn(fsy, 1e-5f));
  float pf = __fdiv_rn(ph, 0.78539816339744830962f);  // f32(pi/4)
  float r  = rintf(pf);                                // half-to-even like jnp.round
  int ip = ((int)r + 4) & 7;                           // mod 8 (value is in [0,8])
  pairb[(size_t)n * HW + p] = (unsigned char)(ip & 3); // SEL_IDS has period 4
}

// K4: NMS (zero-padded neighbor gather) + threshold -> binary edges
__global__ __launch_bounds__(256) void k4_nms(const float* __restrict__ gm,
                                              const unsigned char* __restrict__ pairb,
                                              float* __restrict__ edges) {
  int x = blockIdx.x * 64 + threadIdx.x;
  int y = blockIdx.y * 4  + threadIdx.y;
  int n = blockIdx.z;
  const float* gp = gm + (size_t)n * HW;
  int p = y * WW + x;
  float g = gp[p];
  int pr = pairb[(size_t)n * HW + p];
  // pair -> (dy,dx) for neb0 (cmp <=) and neb1 (cmp <)
  const int dy0[4] = {-1, -1,  0, -1};
  const int dx0[4] = { 0, -1, -1,  1};
  const int dy1[4] = { 1,  1,  0,  1};
  const int dx1[4] = { 0,  1,  1, -1};
  int y0 = y + dy0[pr], x0 = x + dx0[pr];
  int y1 = y + dy1[pr], x1 = x + dx1[pr];
  float n0 = (y0 >= 0 && y0 < HH && x0 >= 0 && x0 < WW) ? gp[y0 * WW + x0] : 0.0f;
  float n1 = (y1 >= 0 && y1 < HH && x1 >= 0 && x1 < WW) ? gp[y1 * WW + x1] : 0.0f;
  bool mask = (g <= n0) || (g < n1);
  edges[(size_t)n * HW + p] = (!mask && (g > 0.1f)) ? 1.0f : 0.0f;
}

extern "C" void kernel_launch(void* const* d_in, const int* in_sizes, int n_in,
                              void* d_out, int out_size, void* d_ws, size_t ws_size,
                              hipStream_t stream) {
  const float* img = (const float*)d_in[0];
  float* out = (float*)d_out;
  char* ws = (char*)d_ws;

  unsigned int* mx    = (unsigned int*)ws;                       // 4 B (padded to 256)
  float*        ssmag = (float*)(ws + 256);                      // 16 MiB
  float*        gm    = (float*)(ws + 256 + 16777216);           // 16 MiB
  unsigned char* pairb = (unsigned char*)(ws + 256 + 2*16777216);// 4 MiB

  float* edges = out;             // 4,194,304 floats
  float* sobel = out + 4194304;   // 8,388,608 floats (n,2,512,512): c0=sy, c1=sx

  hipMemsetAsync(mx, 0, 4, stream);
  k1_sumsq<<<dim3(4096), dim3(256), 0, stream>>>(img, ssmag, mx);
  k2_norm <<<dim3(4096), dim3(256), 0, stream>>>(ssmag, mx);
  dim3 blk(64, 4, 1), grd(8, 128, 16);
  k3_sobel<<<grd, blk, 0, stream>>>(ssmag, sobel, gm, pairb);
  k4_nms  <<<grd, blk, 0, stream>>>(gm, pairb, edges);
}

// Round 3
// 149.055 us; speedup vs baseline: 1.2787x; 1.2787x over previous
//
#include <hip/hip_runtime.h>
#include <math.h>

#define HH 512
#define WW 512
#define HW (HH*WW)   // 262144

// Sobel weights, replicating numpy f32 arithmetic exactly:
// S[i][j] = f32( f32(x/den) / 6 ), x=i-2, y=j-2, den = x*x+y*y except y==0 col -> 1
__device__ __constant__ float WS5[25] = {
  -2.0f/8.0f/6.0f, -2.0f/5.0f/6.0f, -2.0f/1.0f/6.0f, -2.0f/5.0f/6.0f, -2.0f/8.0f/6.0f,
  -1.0f/5.0f/6.0f, -1.0f/2.0f/6.0f, -1.0f/1.0f/6.0f, -1.0f/2.0f/6.0f, -1.0f/5.0f/6.0f,
   0.0f,            0.0f,            0.0f,            0.0f,            0.0f,
   1.0f/5.0f/6.0f,  1.0f/2.0f/6.0f,  1.0f/1.0f/6.0f,  1.0f/2.0f/6.0f,  1.0f/5.0f/6.0f,
   2.0f/8.0f/6.0f,  2.0f/5.0f/6.0f,  2.0f/1.0f/6.0f,  2.0f/5.0f/6.0f,  2.0f/8.0f/6.0f
};

__device__ __forceinline__ int refl(int i) {
  if (i < 0) return -i;
  if (i >= HH) return 2*HH - 2 - i;
  return i;
}

__device__ __forceinline__ float sumsq3(float r, float g, float b) {
  return __fadd_rn(__fadd_rn(__fmul_rn(r,r), __fmul_rn(g,g)), __fmul_rn(b,b));
}

// K1: sumsq over 3 channels (stored for k2) + per-block partial max.
// NO single-address atomics (R1's 4096-block atomicMax serialized at ~13ns/op
// = the observed 54us).  Max over same multiset => bit-identical scalar.
__global__ __launch_bounds__(256) void k1_sumsq(const float* __restrict__ img,
                                                float* __restrict__ ss,
                                                float* __restrict__ partials) {
  int gid = blockIdx.x * 256 + threadIdx.x;   // 0 .. 1048575 (float4 granules)
  int n  = gid >> 16;                         // 65536 float4 per image plane
  int p4 = gid & 65535;
  const float* base = img + (size_t)n * 3 * HW;
  float4 r = ((const float4*)(base        ))[p4];
  float4 g = ((const float4*)(base +   HW ))[p4];
  float4 b = ((const float4*)(base + 2*HW ))[p4];
  float4 s;
  s.x = sumsq3(r.x, g.x, b.x);
  s.y = sumsq3(r.y, g.y, b.y);
  s.z = sumsq3(r.z, g.z, b.z);
  s.w = sumsq3(r.w, g.w, b.w);
  ((float4*)ss)[gid] = s;

  float m = fmaxf(fmaxf(s.x, s.y), fmaxf(s.z, s.w));
  #pragma unroll
  for (int off = 32; off > 0; off >>= 1)
    m = fmaxf(m, __shfl_down(m, off));
  __shared__ float sm[4];
  int lane = threadIdx.x & 63, wv = threadIdx.x >> 6;
  if (lane == 0) sm[wv] = m;
  __syncthreads();
  if (threadIdx.x == 0)
    partials[blockIdx.x] = fmaxf(fmaxf(sm[0], sm[1]), fmaxf(sm[2], sm[3]));
}

// K1b: reduce 4096 partials -> ssmax (single block, no atomics)
__global__ __launch_bounds__(256) void k1b_reduce(const float* __restrict__ partials,
                                                  float* __restrict__ ssmax) {
  float m = 0.0f;
  #pragma unroll
  for (int i = 0; i < 16; ++i)
    m = fmaxf(m, partials[threadIdx.x + 256 * i]);
  #pragma unroll
  for (int off = 32; off > 0; off >>= 1)
    m = fmaxf(m, __shfl_down(m, off));
  __shared__ float sm[4];
  int lane = threadIdx.x & 63, wv = threadIdx.x >> 6;
  if (lane == 0) sm[wv] = m;
  __syncthreads();
  if (threadIdx.x == 0)
    ssmax[0] = fmaxf(fmaxf(sm[0], sm[1]), fmaxf(sm[2], sm[3]));
}

// K2: mag = sqrt(ss) / sqrt(max_ss), in place — SOURCE-IDENTICAL to R1 k2
__global__ __launch_bounds__(256) void k2_norm(float* __restrict__ ssmag,
                                               const float* __restrict__ ssmax) {
  int gid = blockIdx.x * 256 + threadIdx.x;
  float mm = sqrtf(ssmax[0]);
  float4 s = ((const float4*)ssmag)[gid];
  float4 o;
  o.x = __fdiv_rn(sqrtf(s.x), mm);
  o.y = __fdiv_rn(sqrtf(s.y), mm);
  o.z = __fdiv_rn(sqrtf(s.z), mm);
  o.w = __fdiv_rn(sqrtf(s.w), mm);
  ((float4*)ssmag)[gid] = o;
}

// K3: 5x5 Sobel (reflect pad, f64 accumulate), grad_mag, phase -> pair index
// SOURCE-IDENTICAL to R1 k3 (including the zero-weight taps in the f64 chain,
// to keep the compiler's contraction decisions — and hence every bit — the same).
__global__ __launch_bounds__(256) void k3_sobel(const float* __restrict__ mag,
                                                float* __restrict__ sobel_out,
                                                float* __restrict__ gm,
                                                unsigned char* __restrict__ pairb) {
  int x = blockIdx.x * 64 + threadIdx.x;
  int y = blockIdx.y * 4  + threadIdx.y;
  int n = blockIdx.z;
  const float* mp = mag + (size_t)n * HW;
  double asy = 0.0, asx = 0.0;
  #pragma unroll
  for (int a = 0; a < 5; ++a) {
    int ry = refl(y + a - 2);
    const float* row = mp + ry * WW;
    #pragma unroll
    for (int b = 0; b < 5; ++b) {
      int rx = refl(x + b - 2);
      double v = (double)row[rx];
      asy += v * (double)WS5[a*5 + b];   // W_SY = S
      asx += v * (double)WS5[b*5 + a];   // W_SX = S^T
    }
  }
  float fsy = (float)asy, fsx = (float)asx;
  int p = y * WW + x;
  sobel_out[(size_t)n * 2 * HW + p]      = fsy;  // channel 0: sobel_y
  sobel_out[(size_t)n * 2 * HW + HW + p] = fsx;  // channel 1: sobel_x
  float g = sqrtf(__fadd_rn(__fmul_rn(fsx, fsx), __fmul_rn(fsy, fsy)));
  gm[(size_t)n * HW + p] = g;
  float ph = atan2f(fsx, __fadd_rn(fsy, 1e-5f));
  float pf = __fdiv_rn(ph, 0.78539816339744830962f);  // f32(pi/4)
  float r  = rintf(pf);                                // half-to-even like jnp.round
  int ip = ((int)r + 4) & 7;                           // mod 8 (value is in [0,8])
  pairb[(size_t)n * HW + p] = (unsigned char)(ip & 3); // SEL_IDS has period 4
}

// K4: NMS (zero-padded neighbor gather) + threshold — SOURCE-IDENTICAL to R1 k4
__global__ __launch_bounds__(256) void k4_nms(const float* __restrict__ gm,
                                              const unsigned char* __restrict__ pairb,
                                              float* __restrict__ edges) {
  int x = blockIdx.x * 64 + threadIdx.x;
  int y = blockIdx.y * 4  + threadIdx.y;
  int n = blockIdx.z;
  const float* gp = gm + (size_t)n * HW;
  int p = y * WW + x;
  float g = gp[p];
  int pr = pairb[(size_t)n * HW + p];
  const int dy0[4] = {-1, -1,  0, -1};
  const int dx0[4] = { 0, -1, -1,  1};
  const int dy1[4] = { 1,  1,  0,  1};
  const int dx1[4] = { 0,  1,  1, -1};
  int y0 = y + dy0[pr], x0 = x + dx0[pr];
  int y1 = y + dy1[pr], x1 = x + dx1[pr];
  float n0 = (y0 >= 0 && y0 < HH && x0 >= 0 && x0 < WW) ? gp[y0 * WW + x0] : 0.0f;
  float n1 = (y1 >= 0 && y1 < HH && x1 >= 0 && x1 < WW) ? gp[y1 * WW + x1] : 0.0f;
  bool mask = (g <= n0) || (g < n1);
  edges[(size_t)n * HW + p] = (!mask && (g > 0.1f)) ? 1.0f : 0.0f;
}

extern "C" void kernel_launch(void* const* d_in, const int* in_sizes, int n_in,
                              void* d_out, int out_size, void* d_ws, size_t ws_size,
                              hipStream_t stream) {
  const float* img = (const float*)d_in[0];
  float* out = (float*)d_out;
  char* ws = (char*)d_ws;

  float* ssmax    = (float*)ws;                     // 4 B (region padded to 256 B)
  float* partials = (float*)(ws + 256);             // 4096 floats = 16 KiB
  float* ssmag    = (float*)(ws + 256 + 16384);     // 16 MiB
  float* gm       = (float*)(ws + 256 + 16384 + 16777216);      // 16 MiB
  unsigned char* pairb = (unsigned char*)(ws + 256 + 16384 + 2*16777216); // 4 MiB

  float* edges = out;             // (16,1,512,512)
  float* sobel = out + 4194304;   // (16,2,512,512): c0=sy, c1=sx

  k1_sumsq  <<<dim3(4096), dim3(256), 0, stream>>>(img, ssmag, partials);
  k1b_reduce<<<dim3(1),    dim3(256), 0, stream>>>(partials, ssmax);
  k2_norm   <<<dim3(4096), dim3(256), 0, stream>>>(ssmag, ssmax);
  dim3 blk(64, 4, 1), grd(8, 128, 16);
  k3_sobel<<<grd, blk, 0, stream>>>(ssmag, sobel, gm, pairb);
  k4_nms  <<<grd, blk, 0, stream>>>(gm, pairb, edges);
}

// Round 4
// 142.942 us; speedup vs baseline: 1.3334x; 1.0428x over previous
//
#include <hip/hip_runtime.h>
#include <math.h>

#define HH 512
#define WW 512
#define HW (HH*WW)   // 262144

// Sobel weights, replicating numpy f32 arithmetic exactly:
// S[i][j] = f32( f32(x/den) / 6 ), x=i-2, y=j-2, den = x*x+y*y except y==0 col -> 1
__device__ __constant__ float WS5[25] = {
  -2.0f/8.0f/6.0f, -2.0f/5.0f/6.0f, -2.0f/1.0f/6.0f, -2.0f/5.0f/6.0f, -2.0f/8.0f/6.0f,
  -1.0f/5.0f/6.0f, -1.0f/2.0f/6.0f, -1.0f/1.0f/6.0f, -1.0f/2.0f/6.0f, -1.0f/5.0f/6.0f,
   0.0f,            0.0f,            0.0f,            0.0f,            0.0f,
   1.0f/5.0f/6.0f,  1.0f/2.0f/6.0f,  1.0f/1.0f/6.0f,  1.0f/2.0f/6.0f,  1.0f/5.0f/6.0f,
   2.0f/8.0f/6.0f,  2.0f/5.0f/6.0f,  2.0f/1.0f/6.0f,  2.0f/5.0f/6.0f,  2.0f/8.0f/6.0f
};

__device__ __forceinline__ int refl(int i) {
  if (i < 0) return -i;
  if (i >= HH) return 2*HH - 2 - i;
  return i;
}

__device__ __forceinline__ float sumsq3(float r, float g, float b) {
  return __fadd_rn(__fadd_rn(__fmul_rn(r,r), __fmul_rn(g,g)), __fmul_rn(b,b));
}

// K1: sumsq over 3 channels (stored for k3) + per-block partial max (no atomics)
__global__ __launch_bounds__(256) void k1_sumsq(const float* __restrict__ img,
                                                float* __restrict__ ss,
                                                float* __restrict__ partials) {
  int gid = blockIdx.x * 256 + threadIdx.x;   // 0 .. 1048575 (float4 granules)
  int n  = gid >> 16;                         // 65536 float4 per image plane
  int p4 = gid & 65535;
  const float* base = img + (size_t)n * 3 * HW;
  float4 r = ((const float4*)(base        ))[p4];
  float4 g = ((const float4*)(base +   HW ))[p4];
  float4 b = ((const float4*)(base + 2*HW ))[p4];
  float4 s;
  s.x = sumsq3(r.x, g.x, b.x);
  s.y = sumsq3(r.y, g.y, b.y);
  s.z = sumsq3(r.z, g.z, b.z);
  s.w = sumsq3(r.w, g.w, b.w);
  ((float4*)ss)[gid] = s;

  float m = fmaxf(fmaxf(s.x, s.y), fmaxf(s.z, s.w));
  #pragma unroll
  for (int off = 32; off > 0; off >>= 1)
    m = fmaxf(m, __shfl_down(m, off));
  __shared__ float sm[4];
  int lane = threadIdx.x & 63, wv = threadIdx.x >> 6;
  if (lane == 0) sm[wv] = m;
  __syncthreads();
  if (threadIdx.x == 0)
    partials[blockIdx.x] = fmaxf(fmaxf(sm[0], sm[1]), fmaxf(sm[2], sm[3]));
}

// K1b: reduce 4096 partials -> ssmax (single block, no atomics)
__global__ __launch_bounds__(256) void k1b_reduce(const float* __restrict__ partials,
                                                  float* __restrict__ ssmax) {
  float m = 0.0f;
  #pragma unroll
  for (int i = 0; i < 16; ++i)
    m = fmaxf(m, partials[threadIdx.x + 256 * i]);
  #pragma unroll
  for (int off = 32; off > 0; off >>= 1)
    m = fmaxf(m, __shfl_down(m, off));
  __shared__ float sm[4];
  int lane = threadIdx.x & 63, wv = threadIdx.x >> 6;
  if (lane == 0) sm[wv] = m;
  __syncthreads();
  if (threadIdx.x == 0)
    ssmax[0] = fmaxf(fmaxf(sm[0], sm[1]), fmaxf(sm[2], sm[3]));
}

// K3: normalize (folded from k2, bit-identical formula) + 5x5 Sobel from an
// LDS-staged mag tile (f64 accumulate, FULL 25 taps, accumulation source text
// identical to R3), grad_mag, phase -> pair index.
// Output tile 64x4 per block (same mapping as R3); halo tile 8x68.
__global__ __launch_bounds__(256) void k3_sobel(const float* __restrict__ ss,
                                                const float* __restrict__ ssmax,
                                                float* __restrict__ sobel_out,
                                                float* __restrict__ gm,
                                                unsigned char* __restrict__ pairb) {
  __shared__ float magS[8 * 68];
  int tx = threadIdx.x;            // 0..63
  int ty = threadIdx.y;            // 0..3
  int x0 = blockIdx.x * 64;
  int y0 = blockIdx.y * 4;
  int n  = blockIdx.z;
  const float* sp = ss + (size_t)n * HW;
  float mm = sqrtf(ssmax[0]);

  // stage normalized mag over rows [y0-2, y0+6), cols [x0-2, x0+66)
  int tid = ty * 64 + tx;
  for (int i = tid; i < 8 * 68; i += 256) {
    int r = i / 68, c = i - r * 68;
    int gy = refl(y0 - 2 + r);
    int gx = refl(x0 - 2 + c);
    magS[i] = __fdiv_rn(sqrtf(sp[gy * WW + gx]), mm);   // bit-identical to R3 k2
  }
  __syncthreads();

  int x = x0 + tx;
  int y = y0 + ty;
  double asy = 0.0, asx = 0.0;
  #pragma unroll
  for (int a = 0; a < 5; ++a) {
    #pragma unroll
    for (int b = 0; b < 5; ++b) {
      double v = (double)magS[(ty + a) * 68 + (tx + b)];
      asy += v * (double)WS5[a*5 + b];   // W_SY = S
      asx += v * (double)WS5[b*5 + a];   // W_SX = S^T
    }
  }
  float fsy = (float)asy, fsx = (float)asx;
  int p = y * WW + x;
  sobel_out[(size_t)n * 2 * HW + p]      = fsy;  // channel 0: sobel_y
  sobel_out[(size_t)n * 2 * HW + HW + p] = fsx;  // channel 1: sobel_x
  float g = sqrtf(__fadd_rn(__fmul_rn(fsx, fsx), __fmul_rn(fsy, fsy)));
  gm[(size_t)n * HW + p] = g;
  float ph = atan2f(fsx, __fadd_rn(fsy, 1e-5f));
  float pf = __fdiv_rn(ph, 0.78539816339744830962f);  // f32(pi/4)
  float r  = rintf(pf);                                // half-to-even like jnp.round
  int ip = ((int)r + 4) & 7;                           // mod 8 (value is in [0,8])
  pairb[(size_t)n * HW + p] = (unsigned char)(ip & 3); // SEL_IDS has period 4
}

// K4: NMS (zero-padded neighbor gather) + threshold — SOURCE-IDENTICAL to R3 k4
__global__ __launch_bounds__(256) void k4_nms(const float* __restrict__ gm,
                                              const unsigned char* __restrict__ pairb,
                                              float* __restrict__ edges) {
  int x = blockIdx.x * 64 + threadIdx.x;
  int y = blockIdx.y * 4  + threadIdx.y;
  int n = blockIdx.z;
  const float* gp = gm + (size_t)n * HW;
  int p = y * WW + x;
  float g = gp[p];
  int pr = pairb[(size_t)n * HW + p];
  const int dy0[4] = {-1, -1,  0, -1};
  const int dx0[4] = { 0, -1, -1,  1};
  const int dy1[4] = { 1,  1,  0,  1};
  const int dx1[4] = { 0,  1,  1, -1};
  int y0 = y + dy0[pr], x0 = x + dx0[pr];
  int y1 = y + dy1[pr], x1 = x + dx1[pr];
  float n0 = (y0 >= 0 && y0 < HH && x0 >= 0 && x0 < WW) ? gp[y0 * WW + x0] : 0.0f;
  float n1 = (y1 >= 0 && y1 < HH && x1 >= 0 && x1 < WW) ? gp[y1 * WW + x1] : 0.0f;
  bool mask = (g <= n0) || (g < n1);
  edges[(size_t)n * HW + p] = (!mask && (g > 0.1f)) ? 1.0f : 0.0f;
}

extern "C" void kernel_launch(void* const* d_in, const int* in_sizes, int n_in,
                              void* d_out, int out_size, void* d_ws, size_t ws_size,
                              hipStream_t stream) {
  const float* img = (const float*)d_in[0];
  float* out = (float*)d_out;
  char* ws = (char*)d_ws;

  float* ssmax    = (float*)ws;                     // 4 B (region padded to 256 B)
  float* partials = (float*)(ws + 256);             // 4096 floats = 16 KiB
  float* ssbuf    = (float*)(ws + 256 + 16384);     // 16 MiB
  float* gm       = (float*)(ws + 256 + 16384 + 16777216);      // 16 MiB
  unsigned char* pairb = (unsigned char*)(ws + 256 + 16384 + 2*16777216); // 4 MiB

  float* edges = out;             // (16,1,512,512)
  float* sobel = out + 4194304;   // (16,2,512,512): c0=sy, c1=sx

  k1_sumsq  <<<dim3(4096), dim3(256), 0, stream>>>(img, ssbuf, partials);
  k1b_reduce<<<dim3(1),    dim3(256), 0, stream>>>(partials, ssmax);
  dim3 blk(64, 4, 1), grd(8, 128, 16);
  k3_sobel<<<grd, blk, 0, stream>>>(ssbuf, ssmax, sobel, gm, pairb);
  k4_nms  <<<grd, blk, 0, stream>>>(gm, pairb, edges);
}

// Round 5
// 138.422 us; speedup vs baseline: 1.3769x; 1.0327x over previous
//
#include <hip/hip_runtime.h>
#include <math.h>

#define HH 512
#define WW 512
#define HW (HH*WW)   // 262144

// Sobel weights, replicating numpy f32 arithmetic exactly:
// S[i][j] = f32( f32(x/den) / 6 ), x=i-2, y=j-2, den = x*x+y*y except y==0 col -> 1
__device__ __constant__ float WS5[25] = {
  -2.0f/8.0f/6.0f, -2.0f/5.0f/6.0f, -2.0f/1.0f/6.0f, -2.0f/5.0f/6.0f, -2.0f/8.0f/6.0f,
  -1.0f/5.0f/6.0f, -1.0f/2.0f/6.0f, -1.0f/1.0f/6.0f, -1.0f/2.0f/6.0f, -1.0f/5.0f/6.0f,
   0.0f,            0.0f,            0.0f,            0.0f,            0.0f,
   1.0f/5.0f/6.0f,  1.0f/2.0f/6.0f,  1.0f/1.0f/6.0f,  1.0f/2.0f/6.0f,  1.0f/5.0f/6.0f,
   2.0f/8.0f/6.0f,  2.0f/5.0f/6.0f,  2.0f/1.0f/6.0f,  2.0f/5.0f/6.0f,  2.0f/8.0f/6.0f
};

__device__ __forceinline__ int refl(int i) {
  if (i < 0) return -i;
  if (i >= HH) return 2*HH - 2 - i;
  return i;
}

__device__ __forceinline__ float sumsq3(float r, float g, float b) {
  return __fadd_rn(__fadd_rn(__fmul_rn(r,r), __fmul_rn(g,g)), __fmul_rn(b,b));
}

// K1: sumsq over 3 channels (stored for k3) + per-block partial max (no atomics)
__global__ __launch_bounds__(256) void k1_sumsq(const float* __restrict__ img,
                                                float* __restrict__ ss,
                                                float* __restrict__ partials) {
  int gid = blockIdx.x * 256 + threadIdx.x;   // 0 .. 1048575 (float4 granules)
  int n  = gid >> 16;                         // 65536 float4 per image plane
  int p4 = gid & 65535;
  const float* base = img + (size_t)n * 3 * HW;
  float4 r = ((const float4*)(base        ))[p4];
  float4 g = ((const float4*)(base +   HW ))[p4];
  float4 b = ((const float4*)(base + 2*HW ))[p4];
  float4 s;
  s.x = sumsq3(r.x, g.x, b.x);
  s.y = sumsq3(r.y, g.y, b.y);
  s.z = sumsq3(r.z, g.z, b.z);
  s.w = sumsq3(r.w, g.w, b.w);
  ((float4*)ss)[gid] = s;

  float m = fmaxf(fmaxf(s.x, s.y), fmaxf(s.z, s.w));
  #pragma unroll
  for (int off = 32; off > 0; off >>= 1)
    m = fmaxf(m, __shfl_down(m, off));
  __shared__ float sm[4];
  int lane = threadIdx.x & 63, wv = threadIdx.x >> 6;
  if (lane == 0) sm[wv] = m;
  __syncthreads();
  if (threadIdx.x == 0)
    partials[blockIdx.x] = fmaxf(fmaxf(sm[0], sm[1]), fmaxf(sm[2], sm[3]));
}

// K1b: reduce 4096 partials -> ssmax (single block, no atomics)
__global__ __launch_bounds__(256) void k1b_reduce(const float* __restrict__ partials,
                                                  float* __restrict__ ssmax) {
  float m = 0.0f;
  #pragma unroll
  for (int i = 0; i < 16; ++i)
    m = fmaxf(m, partials[threadIdx.x + 256 * i]);
  #pragma unroll
  for (int off = 32; off > 0; off >>= 1)
    m = fmaxf(m, __shfl_down(m, off));
  __shared__ float sm[4];
  int lane = threadIdx.x & 63, wv = threadIdx.x >> 6;
  if (lane == 0) sm[wv] = m;
  __syncthreads();
  if (threadIdx.x == 0)
    ssmax[0] = fmaxf(fmaxf(sm[0], sm[1]), fmaxf(sm[2], sm[3]));
}

// K3: normalize + 5x5 Sobel + grad_mag + phase->pair, register-blocked:
// each thread computes a vertical strip of 4 pixels (tile 64x16 per block).
// Per-pixel f64 accumulation TEXT IS VERBATIM R4 (same 25-term order, same
// staged values) -> bit-identical outputs; the overlap of the 4 windows lets
// the compiler CSE ~60% of the LDS loads / f64 converts.
__global__ __launch_bounds__(256) void k3_sobel(const float* __restrict__ ss,
                                                const float* __restrict__ ssmax,
                                                float* __restrict__ sobel_out,
                                                float* __restrict__ gm,
                                                unsigned char* __restrict__ pairb) {
  __shared__ float magS[20 * 68];  // rows [y0-2, y0+18), cols [x0-2, x0+66)
  int tx = threadIdx.x;            // 0..63
  int ty = threadIdx.y;            // 0..3
  int x0 = blockIdx.x * 64;
  int y0 = blockIdx.y * 16;
  int n  = blockIdx.z;
  const float* sp = ss + (size_t)n * HW;
  float mm = sqrtf(ssmax[0]);

  int tid = ty * 64 + tx;
  for (int i = tid; i < 20 * 68; i += 256) {
    int r = i / 68, c = i - r * 68;
    int gy = refl(y0 - 2 + r);
    int gx = refl(x0 - 2 + c);
    magS[i] = __fdiv_rn(sqrtf(sp[gy * WW + gx]), mm);   // bit-identical to R4
  }
  __syncthreads();

  int x = x0 + tx;
  #pragma unroll
  for (int dy = 0; dy < 4; ++dy) {
    int r = 4 * ty + dy;           // tile-local output row, 0..15
    int y = y0 + r;
    double asy = 0.0, asx = 0.0;
    #pragma unroll
    for (int a = 0; a < 5; ++a) {
      #pragma unroll
      for (int b = 0; b < 5; ++b) {
        double v = (double)magS[(r + a) * 68 + (tx + b)];
        asy += v * (double)WS5[a*5 + b];   // W_SY = S
        asx += v * (double)WS5[b*5 + a];   // W_SX = S^T
      }
    }
    float fsy = (float)asy, fsx = (float)asx;
    int p = y * WW + x;
    sobel_out[(size_t)n * 2 * HW + p]      = fsy;  // channel 0: sobel_y
    sobel_out[(size_t)n * 2 * HW + HW + p] = fsx;  // channel 1: sobel_x
    float g = sqrtf(__fadd_rn(__fmul_rn(fsx, fsx), __fmul_rn(fsy, fsy)));
    gm[(size_t)n * HW + p] = g;
    float ph = atan2f(fsx, __fadd_rn(fsy, 1e-5f));
    float pf = __fdiv_rn(ph, 0.78539816339744830962f);  // f32(pi/4)
    float rr = rintf(pf);                                // half-to-even like jnp.round
    int ip = ((int)rr + 4) & 7;                          // mod 8 (value is in [0,8])
    pairb[(size_t)n * HW + p] = (unsigned char)(ip & 3); // SEL_IDS has period 4
  }
}

// K4: NMS (zero-padded neighbor gather) + threshold — SOURCE-IDENTICAL to R4 k4
__global__ __launch_bounds__(256) void k4_nms(const float* __restrict__ gm,
                                              const unsigned char* __restrict__ pairb,
                                              float* __restrict__ edges) {
  int x = blockIdx.x * 64 + threadIdx.x;
  int y = blockIdx.y * 4  + threadIdx.y;
  int n = blockIdx.z;
  const float* gp = gm + (size_t)n * HW;
  int p = y * WW + x;
  float g = gp[p];
  int pr = pairb[(size_t)n * HW + p];
  const int dy0[4] = {-1, -1,  0, -1};
  const int dx0[4] = { 0, -1, -1,  1};
  const int dy1[4] = { 1,  1,  0,  1};
  const int dx1[4] = { 0,  1,  1, -1};
  int y0 = y + dy0[pr], x0 = x + dx0[pr];
  int y1 = y + dy1[pr], x1 = x + dx1[pr];
  float n0 = (y0 >= 0 && y0 < HH && x0 >= 0 && x0 < WW) ? gp[y0 * WW + x0] : 0.0f;
  float n1 = (y1 >= 0 && y1 < HH && x1 >= 0 && x1 < WW) ? gp[y1 * WW + x1] : 0.0f;
  bool mask = (g <= n0) || (g < n1);
  edges[(size_t)n * HW + p] = (!mask && (g > 0.1f)) ? 1.0f : 0.0f;
}

extern "C" void kernel_launch(void* const* d_in, const int* in_sizes, int n_in,
                              void* d_out, int out_size, void* d_ws, size_t ws_size,
                              hipStream_t stream) {
  const float* img = (const float*)d_in[0];
  float* out = (float*)d_out;
  char* ws = (char*)d_ws;

  float* ssmax    = (float*)ws;                     // 4 B (region padded to 256 B)
  float* partials = (float*)(ws + 256);             // 4096 floats = 16 KiB
  float* ssbuf    = (float*)(ws + 256 + 16384);     // 16 MiB
  float* gm       = (float*)(ws + 256 + 16384 + 16777216);      // 16 MiB
  unsigned char* pairb = (unsigned char*)(ws + 256 + 16384 + 2*16777216); // 4 MiB

  float* edges = out;             // (16,1,512,512)
  float* sobel = out + 4194304;   // (16,2,512,512): c0=sy, c1=sx

  k1_sumsq  <<<dim3(4096), dim3(256), 0, stream>>>(img, ssbuf, partials);
  k1b_reduce<<<dim3(1),    dim3(256), 0, stream>>>(partials, ssmax);
  k3_sobel<<<dim3(8, 32, 16), dim3(64, 4), 0, stream>>>(ssbuf, ssmax, sobel, gm, pairb);
  k4_nms  <<<dim3(8, 128, 16), dim3(64, 4), 0, stream>>>(gm, pairb, edges);
}

// Round 6
// 131.130 us; speedup vs baseline: 1.4535x; 1.0556x over previous
//
#include <hip/hip_runtime.h>
#include <math.h>

#define HH 512
#define WW 512
#define HW (HH*WW)   // 262144

__device__ __forceinline__ int refl(int i) {
  if (i < 0) return -i;
  if (i >= HH) return 2*HH - 2 - i;
  return i;
}

__device__ __forceinline__ float sumsq3(float r, float g, float b) {
  return __fadd_rn(__fadd_rn(__fmul_rn(r,r), __fmul_rn(g,g)), __fmul_rn(b,b));
}

// K1: sumsq over 3 channels (stored for k3) + per-block partial max (no atomics)
__global__ __launch_bounds__(256) void k1_sumsq(const float* __restrict__ img,
                                                float* __restrict__ ss,
                                                float* __restrict__ partials) {
  int gid = blockIdx.x * 256 + threadIdx.x;   // 0 .. 1048575 (float4 granules)
  int n  = gid >> 16;                         // 65536 float4 per image plane
  int p4 = gid & 65535;
  const float* base = img + (size_t)n * 3 * HW;
  float4 r = ((const float4*)(base        ))[p4];
  float4 g = ((const float4*)(base +   HW ))[p4];
  float4 b = ((const float4*)(base + 2*HW ))[p4];
  float4 s;
  s.x = sumsq3(r.x, g.x, b.x);
  s.y = sumsq3(r.y, g.y, b.y);
  s.z = sumsq3(r.z, g.z, b.z);
  s.w = sumsq3(r.w, g.w, b.w);
  ((float4*)ss)[gid] = s;

  float m = fmaxf(fmaxf(s.x, s.y), fmaxf(s.z, s.w));
  #pragma unroll
  for (int off = 32; off > 0; off >>= 1)
    m = fmaxf(m, __shfl_down(m, off));
  __shared__ float sm[4];
  int lane = threadIdx.x & 63, wv = threadIdx.x >> 6;
  if (lane == 0) sm[wv] = m;
  __syncthreads();
  if (threadIdx.x == 0)
    partials[blockIdx.x] = fmaxf(fmaxf(sm[0], sm[1]), fmaxf(sm[2], sm[3]));
}

// K1b: reduce 4096 partials -> ssmax (single block, no atomics)
__global__ __launch_bounds__(256) void k1b_reduce(const float* __restrict__ partials,
                                                  float* __restrict__ ssmax) {
  float m = 0.0f;
  #pragma unroll
  for (int i = 0; i < 16; ++i)
    m = fmaxf(m, partials[threadIdx.x + 256 * i]);
  #pragma unroll
  for (int off = 32; off > 0; off >>= 1)
    m = fmaxf(m, __shfl_down(m, off));
  __shared__ float sm[4];
  int lane = threadIdx.x & 63, wv = threadIdx.x >> 6;
  if (lane == 0) sm[wv] = m;
  __syncthreads();
  if (threadIdx.x == 0)
    ssmax[0] = fmaxf(fmaxf(sm[0], sm[1]), fmaxf(sm[2], sm[3]));
}

// K3: normalize + 5x5 Sobel + grad_mag + phase->pair.
// f64 accumulation restructured via exact weight symmetries of S:
//   w[4-a][b] = -w[a][b], w[a][4-b] = w[a][b], row a=2 == 0, W_SX = S^T.
// Per-row aggregates (S,T,C,D0,D1) are shared across the thread's 4 pixels.
// f64 reordering perturbs sums by ~1e-16 rel, invisible after f64->f32
// rounding (flip prob ~1e-9/value) — statistically bit-stable vs R5.
__global__ __launch_bounds__(256) void k3_sobel(const float* __restrict__ ss,
                                                const float* __restrict__ ssmax,
                                                float* __restrict__ sobel_out,
                                                float* __restrict__ gm,
                                                unsigned char* __restrict__ pairb) {
  __shared__ float magS[20 * 68];  // rows [y0-2, y0+18), cols [x0-2, x0+66)
  int tx = threadIdx.x;            // 0..63
  int ty = threadIdx.y;            // 0..3
  int x0 = blockIdx.x * 64;
  int y0 = blockIdx.y * 16;
  int n  = blockIdx.z;
  const float* sp = ss + (size_t)n * HW;
  float mm = sqrtf(ssmax[0]);

  int tid = ty * 64 + tx;
  for (int i = tid; i < 20 * 68; i += 256) {
    int r = i / 68, c = i - r * 68;
    int gy = refl(y0 - 2 + r);
    int gx = refl(x0 - 2 + c);
    magS[i] = __fdiv_rn(sqrtf(sp[gy * WW + gx]), mm);   // bit-identical to R5
  }
  __syncthreads();

  // exact f32 weights (numpy-folded), widened to f64 exactly
  const double wA0 = (double)(-2.0f/8.0f/6.0f);
  const double wA1 = (double)(-2.0f/5.0f/6.0f);
  const double wA2 = (double)(-2.0f/1.0f/6.0f);
  const double wB0 = (double)(-1.0f/5.0f/6.0f);
  const double wB1 = (double)(-1.0f/2.0f/6.0f);
  const double wB2 = (double)(-1.0f/1.0f/6.0f);

  // per-row aggregates over the thread's 8-row window (tile rows 4ty..4ty+7)
  double S[8], T[8], C[8], D0[8], D1[8];
  #pragma unroll
  for (int j = 0; j < 8; ++j) {
    const float* rowp = &magS[(4 * ty + j) * 68 + tx];
    double v0 = (double)rowp[0], v1 = (double)rowp[1], v2 = (double)rowp[2],
           v3 = (double)rowp[3], v4 = (double)rowp[4];
    S[j]  = v0 + v4;  T[j]  = v1 + v3;  C[j] = v2;
    D0[j] = v0 - v4;  D1[j] = v1 - v3;
  }

  int x = x0 + tx;
  #pragma unroll
  for (int dy = 0; dy < 4; ++dy) {
    int r = 4 * ty + dy;           // tile-local output row, 0..15
    int y = y0 + r;
    int j = dy;                    // window base in aggregate arrays
    double asy = wA0*(S[j]-S[j+4]) + wA1*(T[j]-T[j+4]) + wA2*(C[j]-C[j+4])
               + wB0*(S[j+1]-S[j+3]) + wB1*(T[j+1]-T[j+3]) + wB2*(C[j+1]-C[j+3]);
    double asx = wA0*(D0[j]+D0[j+4]) + wA1*(D0[j+1]+D0[j+3]) + wA2*D0[j+2]
               + wB0*(D1[j]+D1[j+4]) + wB1*(D1[j+1]+D1[j+3]) + wB2*D1[j+2];
    float fsy = (float)asy, fsx = (float)asx;
    int p = y * WW + x;
    sobel_out[(size_t)n * 2 * HW + p]      = fsy;  // channel 0: sobel_y
    sobel_out[(size_t)n * 2 * HW + HW + p] = fsx;  // channel 1: sobel_x
    float g = sqrtf(__fadd_rn(__fmul_rn(fsx, fsx), __fmul_rn(fsy, fsy)));
    gm[(size_t)n * HW + p] = g;
    float ph = atan2f(fsx, __fadd_rn(fsy, 1e-5f));
    float pf = __fdiv_rn(ph, 0.78539816339744830962f);  // f32(pi/4)
    float rr = rintf(pf);                                // half-to-even like jnp.round
    int ip = ((int)rr + 4) & 7;                          // mod 8 (value is in [0,8])
    pairb[(size_t)n * HW + p] = (unsigned char)(ip & 3); // SEL_IDS has period 4
  }
}

// K4: NMS (zero-padded neighbor gather) + threshold — SOURCE-IDENTICAL to R5 k4
__global__ __launch_bounds__(256) void k4_nms(const float* __restrict__ gm,
                                              const unsigned char* __restrict__ pairb,
                                              float* __restrict__ edges) {
  int x = blockIdx.x * 64 + threadIdx.x;
  int y = blockIdx.y * 4  + threadIdx.y;
  int n = blockIdx.z;
  const float* gp = gm + (size_t)n * HW;
  int p = y * WW + x;
  float g = gp[p];
  int pr = pairb[(size_t)n * HW + p];
  const int dy0[4] = {-1, -1,  0, -1};
  const int dx0[4] = { 0, -1, -1,  1};
  const int dy1[4] = { 1,  1,  0,  1};
  const int dx1[4] = { 0,  1,  1, -1};
  int y0 = y + dy0[pr], x0 = x + dx0[pr];
  int y1 = y + dy1[pr], x1 = x + dx1[pr];
  float n0 = (y0 >= 0 && y0 < HH && x0 >= 0 && x0 < WW) ? gp[y0 * WW + x0] : 0.0f;
  float n1 = (y1 >= 0 && y1 < HH && x1 >= 0 && x1 < WW) ? gp[y1 * WW + x1] : 0.0f;
  bool mask = (g <= n0) || (g < n1);
  edges[(size_t)n * HW + p] = (!mask && (g > 0.1f)) ? 1.0f : 0.0f;
}

extern "C" void kernel_launch(void* const* d_in, const int* in_sizes, int n_in,
                              void* d_out, int out_size, void* d_ws, size_t ws_size,
                              hipStream_t stream) {
  const float* img = (const float*)d_in[0];
  float* out = (float*)d_out;
  char* ws = (char*)d_ws;

  float* ssmax    = (float*)ws;                     // 4 B (region padded to 256 B)
  float* partials = (float*)(ws + 256);             // 4096 floats = 16 KiB
  float* ssbuf    = (float*)(ws + 256 + 16384);     // 16 MiB
  float* gm       = (float*)(ws + 256 + 16384 + 16777216);      // 16 MiB
  unsigned char* pairb = (unsigned char*)(ws + 256 + 16384 + 2*16777216); // 4 MiB

  float* edges = out;             // (16,1,512,512)
  float* sobel = out + 4194304;   // (16,2,512,512): c0=sy, c1=sx

  k1_sumsq  <<<dim3(4096), dim3(256), 0, stream>>>(img, ssbuf, partials);
  k1b_reduce<<<dim3(1),    dim3(256), 0, stream>>>(partials, ssmax);
  k3_sobel<<<dim3(8, 32, 16), dim3(64, 4), 0, stream>>>(ssbuf, ssmax, sobel, gm, pairb);
  k4_nms  <<<dim3(8, 128, 16), dim3(64, 4), 0, stream>>>(gm, pairb, edges);
}